// Round 5
// baseline (1208.758 us; speedup 1.0000x reference)
//
#include <hip/hip_runtime.h>

#define DEV __device__ __forceinline__

typedef __attribute__((ext_vector_type(4))) float f4;
typedef __attribute__((ext_vector_type(8))) __bf16 bfrag;
typedef __attribute__((ext_vector_type(4))) unsigned short us4;
typedef __attribute__((ext_vector_type(8))) unsigned short us8;

// problem constants
#define NTOK   4096
#define DMODEL 2048
#define NEXP   64
#define MAXLD  304
#define NSLOT  19456   // 64*304

DEV unsigned short f2bf(float f){
  union { float f; unsigned int i; } u; u.f = f;
  unsigned int r = u.i + 0x7fffu + ((u.i >> 16) & 1u);
  return (unsigned short)(r >> 16);
}
DEV float bf2f(unsigned short b){
  union { unsigned int i; float f; } u; u.i = ((unsigned int)b) << 16;
  return u.f;
}

DEV void gl_lds16(const unsigned short* g, unsigned short* l){
  __builtin_amdgcn_global_load_lds(
      (const __attribute__((address_space(1))) void*)g,
      (__attribute__((address_space(3))) void*)l, 16, 0, 0);
}

// ============== m201-faithful 4-phase/K-step GEMM: C = A @ B^T =============
// A: M x K bf16, B: N x K bf16 (K-contig). BN=256, BK=64 (one K-step).
// 512 thr = 8 waves (2M x 4N); per-wave (BM/2) x 64 output.
// LDS: 2 dbuf x 2 halves x {A: (BM/2)x64, B: 128x64}. Half-tiles:
// A0=rows[0,BM/2), A1=[BM/2,BM), B0=cols[0,128), B1=[128,256).
// Per K-step 4 phases, one C-quadrant (MQ x 2 frags x K64) each:
//   ph0: read a(mh0)+b(nh0) [12/8 ds], stage B1(t+1), lgkm(part), bar,
//        lgkm0, prio1, MFMA Q00, prio0, bar
//   ph1: read b(nh1) [4], stage A1(t+1), bar, lgkm0, MFMA Q01, bar
//   ph2: read a(mh1) [8/4], stage B0(t+2), bar, lgkm0, MFMA Q11, bar
//   ph3: stage A0(t+2), bar, MFMA Q10, vmcnt(2+ALD), bar
// WAR per half (all waves): B0/B1 last read end ph1; A0/A1 last read end ph2;
// each stage lands >=1 barrier after its target's last read. RAW: the ph3
// vmcnt leaves exactly {B0(t+2),A0(t+2)} outstanding -> certifies ALL of
// step t+1; following s_barrier publishes across waves.
// Swizzle: k-chunk (16B) ^= (row&7), involution applied on the global source
// so global_load_lds dest stays linear; reads land 2 lanes/bank (free).
// EPI: 0 = bf16 out, 1 = f32 out, 2 = f32 out = (acc + addin)*0.5
template<int BM, int EPI>
__global__ __launch_bounds__(512, 1) void gemm2(
    const unsigned short* __restrict__ A, const unsigned short* __restrict__ B,
    void* __restrict__ Cp, const float* __restrict__ addin, int M, int N, int K)
{
  constexpr int ALD = BM / 128;   // gl_lds per thread per A-half-tile (2 or 1)
  constexpr int MQ  = BM / 64;    // m-frags per quadrant (4 or 2)
  constexpr int HR  = BM / 2;     // rows per A half
  __shared__ unsigned short As[2][2][HR * 64];
  __shared__ unsigned short Bs[2][2][128 * 64];

  // bijective XCD swizzle (all call-site grids are multiples of 8)
  const int nwg = gridDim.x * gridDim.y;
  int bid = blockIdx.y * gridDim.x + blockIdx.x;
  bid = (bid & 7) * (nwg >> 3) + (bid >> 3);
  const int bx = bid % gridDim.x, by = bid / gridDim.x;
  const int bm = by * BM, bn = bx * 256;

  const int t = threadIdx.x, lane = t & 63, wave = t >> 6;
  const int ha = wave >> 2;          // this wave's A half
  const int wn = (wave & 3) * 64;
  const int hb = wn >> 7;            // this wave's B half
  const int cb = wn & 127;           // col base within B half
  const int fr = lane & 15, kg = lane >> 4;

  // staging chunk geometry: chunk c -> row c>>3, linear k-chunk c&7,
  // source k-chunk (c&7)^(row&7). c0 = t (rows 0..63), c1 = t+512 (rows 64..127).
  const int r0 = t >> 3;
  const int s0 = (t & 7) ^ (r0 & 7);   // note: (r0+64)&7 == r0&7, so same for c1

#define STG_AH(d_, h_, s_) do {                                                          \
    gl_lds16(A + (long long)(bm + (h_) * HR + r0) * K + (long long)(s_) * 64 + s0 * 8,   \
             &As[d_][h_][(wave * 64) * 8]);                                              \
    if (ALD == 2)                                                                        \
      gl_lds16(A + (long long)(bm + (h_) * HR + r0 + 64) * K + (long long)(s_) * 64 + s0 * 8, \
               &As[d_][h_][(512 + wave * 64) * 8]);                                      \
  } while (0)
#define STG_BH(d_, h_, s_) do {                                                          \
    gl_lds16(B + (long long)(bn + (h_) * 128 + r0) * K + (long long)(s_) * 64 + s0 * 8,  \
             &Bs[d_][h_][(wave * 64) * 8]);                                              \
    gl_lds16(B + (long long)(bn + (h_) * 128 + r0 + 64) * K + (long long)(s_) * 64 + s0 * 8, \
             &Bs[d_][h_][(512 + wave * 64) * 8]);                                        \
  } while (0)

  f4 acc[2 * MQ][4];
#pragma unroll
  for (int m = 0; m < 2 * MQ; ++m)
#pragma unroll
    for (int n = 0; n < 4; ++n) acc[m][n] = f4{0.f, 0.f, 0.f, 0.f};

  const int ns = K >> 6;   // all call sites: ns >= 8

  // prologue: step0 fully + B0/A0 of step1 (rotation-consistent order)
  STG_BH(0, 0, 0); STG_AH(0, 0, 0); STG_BH(0, 1, 0); STG_AH(0, 1, 0);
  STG_BH(1, 0, 1); STG_AH(1, 0, 1);
  asm volatile("s_waitcnt vmcnt(%0)" :: "i"(2 + ALD) : "memory");
  __builtin_amdgcn_s_barrier();

  for (int tt = 0; tt < ns; ++tt){
    const int d = tt & 1, nd = d ^ 1;
    bfrag af[MQ][2], bf[2][2][2];

    // ---- phase 0: Q(0,0) ----
#pragma unroll
    for (int ni = 0; ni < 2; ++ni)
#pragma unroll
      for (int kh = 0; kh < 2; ++kh){
        const int cn = cb + ni * 16 + fr;
        bf[0][ni][kh] = *(const bfrag*)&Bs[d][hb][cn * 64 + ((((kh << 2) | kg) ^ (cn & 7)) << 3)];
      }
#pragma unroll
    for (int mi = 0; mi < MQ; ++mi)
#pragma unroll
      for (int kh = 0; kh < 2; ++kh){
        const int rh = mi * 16 + fr;
        af[mi][kh] = *(const bfrag*)&As[d][ha][rh * 64 + ((((kh << 2) | kg) ^ (rh & 7)) << 3)];
      }
    if (tt + 1 < ns) STG_BH(nd, 1, tt + 1);
    if constexpr (BM == 256) asm volatile("s_waitcnt lgkmcnt(8)");
    else                     asm volatile("s_waitcnt lgkmcnt(4)");
    __builtin_amdgcn_s_barrier();
    asm volatile("s_waitcnt lgkmcnt(0)");
    __builtin_amdgcn_s_setprio(1);
#pragma unroll
    for (int mi = 0; mi < MQ; ++mi)
#pragma unroll
      for (int ni = 0; ni < 2; ++ni)
#pragma unroll
        for (int kh = 0; kh < 2; ++kh)
          acc[mi][ni] = __builtin_amdgcn_mfma_f32_16x16x32_bf16(af[mi][kh], bf[0][ni][kh], acc[mi][ni], 0, 0, 0);
    __builtin_amdgcn_s_setprio(0);
    __builtin_amdgcn_s_barrier();

    // ---- phase 1: Q(0,1) ----
#pragma unroll
    for (int ni = 0; ni < 2; ++ni)
#pragma unroll
      for (int kh = 0; kh < 2; ++kh){
        const int cn = cb + 32 + ni * 16 + fr;
        bf[1][ni][kh] = *(const bfrag*)&Bs[d][hb][cn * 64 + ((((kh << 2) | kg) ^ (cn & 7)) << 3)];
      }
    if (tt + 1 < ns) STG_AH(nd, 1, tt + 1);
    __builtin_amdgcn_s_barrier();
    asm volatile("s_waitcnt lgkmcnt(0)");
    __builtin_amdgcn_s_setprio(1);
#pragma unroll
    for (int mi = 0; mi < MQ; ++mi)
#pragma unroll
      for (int ni = 0; ni < 2; ++ni)
#pragma unroll
        for (int kh = 0; kh < 2; ++kh)
          acc[mi][2 + ni] = __builtin_amdgcn_mfma_f32_16x16x32_bf16(af[mi][kh], bf[1][ni][kh], acc[mi][2 + ni], 0, 0, 0);
    __builtin_amdgcn_s_setprio(0);
    __builtin_amdgcn_s_barrier();

    // ---- phase 2: Q(1,1) ----
#pragma unroll
    for (int mi = 0; mi < MQ; ++mi)
#pragma unroll
      for (int kh = 0; kh < 2; ++kh){
        const int rh = MQ * 16 + mi * 16 + fr;
        af[mi][kh] = *(const bfrag*)&As[d][ha][rh * 64 + ((((kh << 2) | kg) ^ (rh & 7)) << 3)];
      }
    if (tt + 2 < ns) STG_BH(d, 0, tt + 2);
    __builtin_amdgcn_s_barrier();
    asm volatile("s_waitcnt lgkmcnt(0)");
    __builtin_amdgcn_s_setprio(1);
#pragma unroll
    for (int mi = 0; mi < MQ; ++mi)
#pragma unroll
      for (int ni = 0; ni < 2; ++ni)
#pragma unroll
        for (int kh = 0; kh < 2; ++kh)
          acc[MQ + mi][2 + ni] = __builtin_amdgcn_mfma_f32_16x16x32_bf16(af[mi][kh], bf[1][ni][kh], acc[MQ + mi][2 + ni], 0, 0, 0);
    __builtin_amdgcn_s_setprio(0);
    __builtin_amdgcn_s_barrier();

    // ---- phase 3: Q(1,0) ----
    if (tt + 2 < ns) STG_AH(d, 0, tt + 2);
    __builtin_amdgcn_s_barrier();
    __builtin_amdgcn_s_setprio(1);
#pragma unroll
    for (int mi = 0; mi < MQ; ++mi)
#pragma unroll
      for (int ni = 0; ni < 2; ++ni)
#pragma unroll
        for (int kh = 0; kh < 2; ++kh)
          acc[MQ + mi][ni] = __builtin_amdgcn_mfma_f32_16x16x32_bf16(af[mi][kh], bf[0][ni][kh], acc[MQ + mi][ni], 0, 0, 0);
    __builtin_amdgcn_s_setprio(0);
    if (tt + 2 < ns)      asm volatile("s_waitcnt vmcnt(%0)" :: "i"(2 + ALD) : "memory");
    else if (tt + 1 < ns) asm volatile("s_waitcnt vmcnt(0)" ::: "memory");
    if (tt + 1 < ns) __builtin_amdgcn_s_barrier();
  }

  // epilogue: C/D layout col=lane&15, row=(lane>>4)*4+reg
#pragma unroll
  for (int mh = 0; mh < 2; ++mh)
#pragma unroll
    for (int mi = 0; mi < MQ; ++mi){
      const int row0 = bm + ha * HR + mh * (HR / 2) + mi * 16 + kg * 4;
#pragma unroll
      for (int nf = 0; nf < 4; ++nf){
        const int col = bn + wn + nf * 16 + fr;
        f4 v = acc[mh * MQ + mi][nf];
#pragma unroll
        for (int r = 0; r < 4; ++r){
          const long long off = (long long)(row0 + r) * N + col;
          if (EPI == 0)      ((unsigned short*)Cp)[off] = f2bf(v[r]);
          else if (EPI == 1) ((float*)Cp)[off] = v[r];
          else               ((float*)Cp)[off] = (v[r] + addin[off]) * 0.5f;
        }
      }
    }
#undef STG_AH
#undef STG_BH
}

// ---------------- generic 128x128 C = A @ B^T GEMM (bounds-checked) --------
// EPI: 0 = bf16 out, 1 = f32 out, 2 = f32 out = (acc + addin)*0.5
template<int EPI>
__global__ __launch_bounds__(256) void gemm_bt(
    const unsigned short* __restrict__ A, const unsigned short* __restrict__ B,
    void* __restrict__ Cp, const float* __restrict__ addin,
    int M, int N, int K, long long sA, long long sB, long long sC)
{
  __shared__ unsigned short As[128*32];
  __shared__ unsigned short Bs[128*32];
  A += (long long)blockIdx.z * sA;
  B += (long long)blockIdx.z * sB;
  const long long cbase = (long long)blockIdx.z * sC;
  const int bm = blockIdx.y * 128, bn = blockIdx.x * 128;
  const int t = threadIdx.x, wave = t >> 6, lane = t & 63;
  const int wm = (wave >> 1) * 64, wn = (wave & 1) * 64;
  const int fr = lane & 15, kg = lane >> 4;

  f4 acc[4][4];
#pragma unroll
  for (int m = 0; m < 4; ++m)
#pragma unroll
    for (int n = 0; n < 4; ++n)
      acc[m][n] = f4{0.f, 0.f, 0.f, 0.f};

  const int i0 = t, i1 = 256 + t;
  int ar0 = bm + (i0 >> 2); if (ar0 > M - 1) ar0 = M - 1;
  int ar1 = bm + (i1 >> 2); if (ar1 > M - 1) ar1 = M - 1;
  int br0 = bn + (i0 >> 2); if (br0 > N - 1) br0 = N - 1;
  int br1 = bn + (i1 >> 2); if (br1 > N - 1) br1 = N - 1;
  const unsigned short* ap0 = A + (long long)ar0 * K + (i0 & 3) * 8;
  const unsigned short* ap1 = A + (long long)ar1 * K + (i1 & 3) * 8;
  const unsigned short* bp0 = B + (long long)br0 * K + (i0 & 3) * 8;
  const unsigned short* bp1 = B + (long long)br1 * K + (i1 & 3) * 8;
  unsigned short* da0 = As + wave * 512;
  unsigned short* da1 = As + 2048 + wave * 512;
  unsigned short* db0 = Bs + wave * 512;
  unsigned short* db1 = Bs + 2048 + wave * 512;

  for (int k0 = 0; k0 < K; k0 += 32){
    gl_lds16(ap0, da0);
    gl_lds16(ap1, da1);
    gl_lds16(bp0, db0);
    gl_lds16(bp1, db1);
    ap0 += 32; ap1 += 32; bp0 += 32; bp1 += 32;
    __syncthreads();
    bfrag af[4], bfv[4];
#pragma unroll
    for (int m = 0; m < 4; ++m) af[m] = *(const bfrag*)&As[(wm + m*16 + fr)*32 + kg*8];
#pragma unroll
    for (int n = 0; n < 4; ++n) bfv[n] = *(const bfrag*)&Bs[(wn + n*16 + fr)*32 + kg*8];
#pragma unroll
    for (int m = 0; m < 4; ++m)
#pragma unroll
      for (int n = 0; n < 4; ++n)
        acc[m][n] = __builtin_amdgcn_mfma_f32_16x16x32_bf16(af[m], bfv[n], acc[m][n], 0, 0, 0);
    __syncthreads();
  }

#pragma unroll
  for (int m = 0; m < 4; ++m){
    const int row0 = bm + wm + m*16 + kg*4;
#pragma unroll
    for (int n = 0; n < 4; ++n){
      const int col = bn + wn + n*16 + fr;
      if (col < N){
        f4 v = acc[m][n];
#pragma unroll
        for (int r = 0; r < 4; ++r){
          const int row = row0 + r;
          if (row < M){
            const long long off = cbase + (long long)row * N + col;
            if (EPI == 0)      ((unsigned short*)Cp)[off] = f2bf(v[r]);
            else if (EPI == 1) ((float*)Cp)[off] = v[r];
            else               ((float*)Cp)[off] = (v[r] + addin[off]) * 0.5f;
          }
        }
      }
    }
  }
}

// ---------------- f32 -> bf16 convert (vectorized) ----------------
__global__ void cvt_bf16(const float* __restrict__ in, unsigned short* __restrict__ out,
                         long long n4)
{
  long long i = (long long)blockIdx.x * 256 + threadIdx.x;
  if (i >= n4) return;
  float4 v = ((const float4*)in)[i];
  us4 o; o[0] = f2bf(v.x); o[1] = f2bf(v.y); o[2] = f2bf(v.z); o[3] = f2bf(v.w);
  ((us4*)out)[i] = o;
}

// ---------------- [z][R][C] f32 -> [z][C][R] bf16 ----------------
__global__ __launch_bounds__(256) void transpose_cvt(const float* __restrict__ in,
    unsigned short* __restrict__ out, int R, int C)
{
  __shared__ float tile[32][33];
  const long long z = blockIdx.z;
  const float* ip = in + z * (long long)R * C;
  unsigned short* op = out + z * (long long)R * C;
  const int r0 = blockIdx.y * 32, c0 = blockIdx.x * 32;
  const int t = threadIdx.x;
  const int lr = t >> 3, lc = (t & 7) * 4;
  float4 v = *(const float4*)(ip + (long long)(r0 + lr) * C + c0 + lc);
  tile[lr][lc+0] = v.x; tile[lr][lc+1] = v.y; tile[lr][lc+2] = v.z; tile[lr][lc+3] = v.w;
  __syncthreads();
  const int oc = t >> 3, orr = (t & 7) * 4;
  us4 o;
  o[0] = f2bf(tile[orr+0][oc]); o[1] = f2bf(tile[orr+1][oc]);
  o[2] = f2bf(tile[orr+2][oc]); o[3] = f2bf(tile[orr+3][oc]);
  *(us4*)(op + (long long)(c0 + oc) * R + r0 + orr) = o;
}

// ---------------- router: top-4, softmax gating, z-loss ----------------
__global__ void router_topk(const float* __restrict__ logits, int* __restrict__ topk,
                            float* __restrict__ gating, float* __restrict__ zout)
{
  const int t = threadIdx.x, w = t >> 6, lane = t & 63;
  const int n = blockIdx.x * 4 + w;
  const float lg = logits[(long long)n * 64 + lane];
  float z = lg * lg;
#pragma unroll
  for (int off = 32; off; off >>= 1) z += __shfl_xor(z, off);
  __shared__ float zs[4];
  if (lane == 0) zs[w] = z;
  __syncthreads();
  if (t == 0) atomicAdd(zout, (zs[0]+zs[1]+zs[2]+zs[3]) * (0.0001f / 262144.0f));

  float cur = lg;
  float tl[4]; int ti[4];
#pragma unroll
  for (int k = 0; k < 4; ++k){
    float s = cur; int si = lane;
#pragma unroll
    for (int off = 32; off; off >>= 1){
      float so = __shfl_xor(s, off); int io = __shfl_xor(si, off);
      if (so > s || (so == s && io < si)){ s = so; si = io; }
    }
    tl[k] = s; ti[k] = si;
    if (lane == si) cur = -3.0e38f;
  }
  if (lane == 0){
    const float m0 = tl[0];
    const float e0 = __expf(tl[0]-m0), e1 = __expf(tl[1]-m0),
                e2 = __expf(tl[2]-m0), e3 = __expf(tl[3]-m0);
    const float inv = 1.0f / (e0 + e1 + e2 + e3);
    topk[n*4+0] = ti[0]; topk[n*4+1] = ti[1]; topk[n*4+2] = ti[2]; topk[n*4+3] = ti[3];
    gating[n*4+0] = e0*inv; gating[n*4+1] = e1*inv; gating[n*4+2] = e2*inv; gating[n*4+3] = e3*inv;
  }
}

// ---------------- deterministic per-expert rank scan ----------------
__global__ void scan_route(const int* __restrict__ topk, int* __restrict__ gm,
                           int* __restrict__ rev, int* __restrict__ counts)
{
  const int e = blockIdx.x;
  const int t = threadIdx.x, w = t >> 6, lane = t & 63;
  __shared__ int wtot[4];
  int running = 0;
  for (int c = 0; c < 16384; c += 256){
    const int j = c + t;
    const bool p = (topk[j] == e);
    const unsigned long long m = __ballot(p);
    const int prefix = __popcll(m & ((1ull << lane) - 1ull));
    if (lane == 0) wtot[w] = __popcll(m);
    __syncthreads();
    int woff = 0;
#pragma unroll
    for (int i = 0; i < 4; ++i){ if (i < w) woff += wtot[i]; }
    const int btot = wtot[0] + wtot[1] + wtot[2] + wtot[3];
    if (p){
      const int rank = running + woff + prefix;
      gm[j] = (rank < MAXLD) ? (e * MAXLD + rank) : NSLOT;
      if (rank < MAXLD) rev[e * MAXLD + rank] = j >> 2;
    }
    running += btot;
    __syncthreads();
  }
  if (t == 0) counts[e] = running;
}

// ---------------- gather down-projected tokens into expert slots ----------------
__global__ void gather_pad(const unsigned short* __restrict__ down, const int* __restrict__ rev,
                           const int* __restrict__ counts, unsigned short* __restrict__ pad)
{
  const int idx = blockIdx.x * 256 + threadIdx.x;
  const int s = idx >> 6, c8 = (idx & 63) * 8;
  const int e = s / MAXLD;
  const int r = s - e * MAXLD;
  int cnt = counts[e]; if (cnt > MAXLD) cnt = MAXLD;
  us8 v = {0,0,0,0,0,0,0,0};
  if (r < cnt){
    const int tok = rev[s];
    v = *(const us8*)(down + (long long)tok * 512 + c8);
  }
  *(us8*)(pad + (long long)s * 512 + c8) = v;
}

// ---------------- silu(G)*U elementwise ----------------
__global__ void silu_mul(const unsigned short* __restrict__ G, const unsigned short* __restrict__ U,
                         unsigned short* __restrict__ O, long long ldg, long long ldu, long long ldo,
                         long long cols8, long long total)
{
  const long long idx = (long long)blockIdx.x * 256 + threadIdx.x;
  if (idx >= total) return;
  const long long rr = idx / cols8;
  const long long cc = (idx - rr * cols8) * 8;
  us8 g = *(const us8*)(G + rr * ldg + cc);
  us8 u = *(const us8*)(U + rr * ldu + cc);
  us8 o;
#pragma unroll
  for (int j = 0; j < 8; ++j){
    const float gf = bf2f(g[j]);
    const float s = gf / (1.0f + __expf(-gf));
    o[j] = f2bf(s * bf2f(u[j]));
  }
  *(us8*)(O + rr * ldo + cc) = o;
}

// ---------------- gating-weighted combine ----------------
__global__ void combine_moe(const unsigned short* __restrict__ po, const int* __restrict__ gm,
                            const float* __restrict__ gating, unsigned short* __restrict__ routed)
{
  const int idx = blockIdx.x * 256 + threadIdx.x;
  const int n = idx >> 6, c8 = (idx & 63) * 8;
  float acc[8] = {0,0,0,0,0,0,0,0};
#pragma unroll
  for (int k = 0; k < 4; ++k){
    const int slot = gm[n*4 + k];
    if (slot < NSLOT){
      const float gw = gating[n*4 + k];
      us8 v = *(const us8*)(po + (long long)slot * 512 + c8);
#pragma unroll
      for (int j = 0; j < 8; ++j) acc[j] += gw * bf2f(v[j]);
    }
  }
  us8 o;
#pragma unroll
  for (int j = 0; j < 8; ++j) o[j] = f2bf(acc[j]);
  *(us8*)(routed + (long long)n * 512 + c8) = o;
}

// =====================================================================
extern "C" void kernel_launch(void* const* d_in, const int* in_sizes, int n_in,
                              void* d_out, int out_size, void* d_ws, size_t ws_size,
                              hipStream_t stream)
{
  const float* x      = (const float*)d_in[0];
  const float* rw     = (const float*)d_in[1];
  const float* gate_w = (const float*)d_in[2];
  const float* up_w   = (const float*)d_in[3];
  const float* down_w = (const float*)d_in[4];
  const float* w_down = (const float*)d_in[5];
  const float* w_up   = (const float*)d_in[6];
  const float* w12    = (const float*)d_in[7];
  const float* w3     = (const float*)d_in[8];
  float* out = (float*)d_out;

  char* ws = (char*)d_ws;
  unsigned short* HBF   = (unsigned short*)(ws + 0ull);
  unsigned short* RWBF  = (unsigned short*)(ws + 16777216ull);
  unsigned short* GATEB = (unsigned short*)(ws + 17039360ull);
  unsigned short* UPB   = (unsigned short*)(ws + 50593792ull);
  unsigned short* DWB   = (unsigned short*)(ws + 84148224ull);
  unsigned short* WDB   = (unsigned short*)(ws + 117702656ull);
  unsigned short* WUB   = (unsigned short*)(ws + 119799808ull);
  unsigned short* W12T  = (unsigned short*)(ws + 121896960ull);
  unsigned short* W3T   = (unsigned short*)(ws + 323223552ull);
  float*          LOGIT = (float*)(ws + 423886848ull);
  int*            TOPKI = (int*)(ws + 424935424ull);
  float*          GATE4 = (float*)(ws + 425000960ull);
  int*            GM    = (int*)(ws + 425066496ull);
  int*            CNT   = (int*)(ws + 425132032ull);
  int*            REV   = (int*)(ws + 425132288ull);
  unsigned short* GU    = (unsigned short*)(ws + 425210112ull);
  unsigned short* ACTS  = (unsigned short*)(ws + 559427840ull);
  float*          SHRD  = (float*)(ws + 626536704ull);
  unsigned short* DNB   = (unsigned short*)(ws + 660091136ull);
  unsigned short* PAD   = (unsigned short*)(ws + 664285440ull);
  unsigned short* PO    = (unsigned short*)(ws + 684208384ull);
  unsigned short* RTD   = (unsigned short*)(ws + 704131328ull);

  hipMemsetAsync((char*)d_out + 8388608ull * 4, 0, 4, stream);

  // bf16 conversions
  cvt_bf16<<<8192,  256, 0, stream>>>(x,      HBF,   2097152);
  cvt_bf16<<<128,   256, 0, stream>>>(rw,     RWBF,  32768);
  cvt_bf16<<<16384, 256, 0, stream>>>(gate_w, GATEB, 4194304);
  cvt_bf16<<<16384, 256, 0, stream>>>(up_w,   UPB,   4194304);
  cvt_bf16<<<16384, 256, 0, stream>>>(down_w, DWB,   4194304);
  cvt_bf16<<<1024,  256, 0, stream>>>(w_down, WDB,   262144);
  cvt_bf16<<<1024,  256, 0, stream>>>(w_up,   WUB,   262144);
  transpose_cvt<<<dim3(96,16,64), 256, 0, stream>>>(w12, W12T, 512, 3072);
  transpose_cvt<<<dim3(16,48,64), 256, 0, stream>>>(w3,  W3T,  1536, 512);

  // router
  gemm_bt<1><<<dim3(1,32,1), 256, 0, stream>>>(HBF, RWBF, LOGIT, nullptr,
                                               4096, 64, 2048, 0, 0, 0);
  router_topk<<<1024, 256, 0, stream>>>(LOGIT, TOPKI, GATE4, out + 8388608);
  scan_route<<<64, 256, 0, stream>>>(TOPKI, GM, REV, CNT);

  // shared expert (m201-faithful 4-phase GEMMs)
  gemm2<256,0><<<dim3(32,16), 512, 0, stream>>>(HBF, GATEB, GU, nullptr, 4096, 8192, 2048);
  gemm2<256,0><<<dim3(32,16), 512, 0, stream>>>(HBF, UPB, GU + 33554432ull, nullptr, 4096, 8192, 2048);
  silu_mul<<<16384, 256, 0, stream>>>(GU, GU + 33554432ull, ACTS, 8192, 8192, 8192,
                                      1024, 4194304);
  gemm2<128,1><<<dim3(8,32), 512, 0, stream>>>(ACTS, DWB, SHRD, nullptr, 4096, 2048, 8192);

  // MoE path
  gemm_bt<0><<<dim3(4,32,1), 256, 0, stream>>>(HBF, WDB, DNB, nullptr,
                                               4096, 512, 2048, 0, 0, 0);
  gather_pad<<<4864, 256, 0, stream>>>(DNB, REV, CNT, PAD);
  gemm_bt<0><<<dim3(24,3,64), 256, 0, stream>>>(PAD, W12T, GU, nullptr,
                                                304, 3072, 512, 155648, 1572864, 933888);
  silu_mul<<<14592, 256, 0, stream>>>(GU, GU + 1536, ACTS, 3072, 3072, 1536,
                                      192, 3735552);
  gemm_bt<0><<<dim3(4,3,64), 256, 0, stream>>>(ACTS, W3T, PO, nullptr,
                                               304, 512, 1536, 466944, 786432, 155648);
  combine_moe<<<1024, 256, 0, stream>>>(PO, GM, GATE4, RTD);

  // final: out = (shared + routed @ w_up^T) * 0.5
  gemm2<128,2><<<dim3(8,32), 512, 0, stream>>>(RTD, WUB, out, SHRD, 4096, 2048, 512);
}

// Round 6
// 1123.932 us; speedup vs baseline: 1.0755x; 1.0755x over previous
//
#include <hip/hip_runtime.h>

#define DEV __device__ __forceinline__

typedef __attribute__((ext_vector_type(4))) float f4;
typedef __attribute__((ext_vector_type(8))) __bf16 bfrag;
typedef __attribute__((ext_vector_type(4))) unsigned short us4;
typedef __attribute__((ext_vector_type(8))) unsigned short us8;

// problem constants
#define NTOK   4096
#define DMODEL 2048
#define NEXP   64
#define MAXLD  304
#define NSLOT  19456   // 64*304

DEV unsigned short f2bf(float f){
  union { float f; unsigned int i; } u; u.f = f;
  unsigned int r = u.i + 0x7fffu + ((u.i >> 16) & 1u);
  return (unsigned short)(r >> 16);
}
DEV float bf2f(unsigned short b){
  union { unsigned int i; float f; } u; u.i = ((unsigned int)b) << 16;
  return u.f;
}
DEV float silu_f(float g){ return g / (1.0f + __expf(-g)); }

DEV void gl_lds16(const unsigned short* g, unsigned short* l){
  __builtin_amdgcn_global_load_lds(
      (const __attribute__((address_space(1))) void*)g,
      (__attribute__((address_space(3))) void*)l, 16, 0, 0);
}

// ============== 4-phase/K-step GEMM: C = A @ B^T =============
// (schedule identical to round-5 gemm2; epilogue extended)
// EPI: 0 = bf16 out, 1 = f32 out, 2 = f32 out = (acc+addin)*0.5
// EPI 3 = MEGA epilogue: cols [0,16384) are 16-col interleaved (gate,up)
//   pairs -> silu(g)*u -> bf16 ACTS (ld 8192); cols [16384,16896) plain bf16
//   -> DNB (ld 512); cols [16896,16960) f32 -> LOGIT (ld 64); rest dropped.
template<int BM, int EPI>
__global__ __launch_bounds__(512, 1) void gemm2(
    const unsigned short* __restrict__ A, const unsigned short* __restrict__ B,
    void* __restrict__ Cp, const float* __restrict__ addin, int M, int N, int K,
    void* __restrict__ Cp2, void* __restrict__ Cp3)
{
  constexpr int ALD = BM / 128;   // gl_lds per thread per A-half-tile (2 or 1)
  constexpr int MQ  = BM / 64;    // m-frags per quadrant (4 or 2)
  constexpr int HR  = BM / 2;     // rows per A half
  __shared__ unsigned short As[2][2][HR * 64];
  __shared__ unsigned short Bs[2][2][128 * 64];

  // bijective XCD swizzle (all call-site grids are multiples of 8)
  const int nwg = gridDim.x * gridDim.y;
  int bid = blockIdx.y * gridDim.x + blockIdx.x;
  bid = (bid & 7) * (nwg >> 3) + (bid >> 3);
  const int bx = bid % gridDim.x, by = bid / gridDim.x;
  const int bm = by * BM, bn = bx * 256;

  const int t = threadIdx.x, lane = t & 63, wave = t >> 6;
  const int ha = wave >> 2;          // this wave's A half
  const int wn = (wave & 3) * 64;
  const int hb = wn >> 7;            // this wave's B half
  const int cb = wn & 127;           // col base within B half
  const int fr = lane & 15, kg = lane >> 4;

  const int r0 = t >> 3;
  const int s0 = (t & 7) ^ (r0 & 7);

#define STG_AH(d_, h_, s_) do {                                                          \
    gl_lds16(A + (long long)(bm + (h_) * HR + r0) * K + (long long)(s_) * 64 + s0 * 8,   \
             &As[d_][h_][(wave * 64) * 8]);                                              \
    if (ALD == 2)                                                                        \
      gl_lds16(A + (long long)(bm + (h_) * HR + r0 + 64) * K + (long long)(s_) * 64 + s0 * 8, \
               &As[d_][h_][(512 + wave * 64) * 8]);                                      \
  } while (0)
#define STG_BH(d_, h_, s_) do {                                                          \
    gl_lds16(B + (long long)(bn + (h_) * 128 + r0) * K + (long long)(s_) * 64 + s0 * 8,  \
             &Bs[d_][h_][(wave * 64) * 8]);                                              \
    gl_lds16(B + (long long)(bn + (h_) * 128 + r0 + 64) * K + (long long)(s_) * 64 + s0 * 8, \
             &Bs[d_][h_][(512 + wave * 64) * 8]);                                        \
  } while (0)

  f4 acc[2 * MQ][4];
#pragma unroll
  for (int m = 0; m < 2 * MQ; ++m)
#pragma unroll
    for (int n = 0; n < 4; ++n) acc[m][n] = f4{0.f, 0.f, 0.f, 0.f};

  const int ns = K >> 6;

  STG_BH(0, 0, 0); STG_AH(0, 0, 0); STG_BH(0, 1, 0); STG_AH(0, 1, 0);
  STG_BH(1, 0, 1); STG_AH(1, 0, 1);
  asm volatile("s_waitcnt vmcnt(%0)" :: "i"(2 + ALD) : "memory");
  __builtin_amdgcn_s_barrier();

  for (int tt = 0; tt < ns; ++tt){
    const int d = tt & 1, nd = d ^ 1;
    bfrag af[MQ][2], bf[2][2][2];

    // ---- phase 0: Q(0,0) ----
#pragma unroll
    for (int ni = 0; ni < 2; ++ni)
#pragma unroll
      for (int kh = 0; kh < 2; ++kh){
        const int cn = cb + ni * 16 + fr;
        bf[0][ni][kh] = *(const bfrag*)&Bs[d][hb][cn * 64 + ((((kh << 2) | kg) ^ (cn & 7)) << 3)];
      }
#pragma unroll
    for (int mi = 0; mi < MQ; ++mi)
#pragma unroll
      for (int kh = 0; kh < 2; ++kh){
        const int rh = mi * 16 + fr;
        af[mi][kh] = *(const bfrag*)&As[d][ha][rh * 64 + ((((kh << 2) | kg) ^ (rh & 7)) << 3)];
      }
    if (tt + 1 < ns) STG_BH(nd, 1, tt + 1);
    if constexpr (BM == 256) asm volatile("s_waitcnt lgkmcnt(8)");
    else                     asm volatile("s_waitcnt lgkmcnt(4)");
    __builtin_amdgcn_s_barrier();
    asm volatile("s_waitcnt lgkmcnt(0)");
    __builtin_amdgcn_s_setprio(1);
#pragma unroll
    for (int mi = 0; mi < MQ; ++mi)
#pragma unroll
      for (int ni = 0; ni < 2; ++ni)
#pragma unroll
        for (int kh = 0; kh < 2; ++kh)
          acc[mi][ni] = __builtin_amdgcn_mfma_f32_16x16x32_bf16(af[mi][kh], bf[0][ni][kh], acc[mi][ni], 0, 0, 0);
    __builtin_amdgcn_s_setprio(0);
    __builtin_amdgcn_s_barrier();

    // ---- phase 1: Q(0,1) ----
#pragma unroll
    for (int ni = 0; ni < 2; ++ni)
#pragma unroll
      for (int kh = 0; kh < 2; ++kh){
        const int cn = cb + 32 + ni * 16 + fr;
        bf[1][ni][kh] = *(const bfrag*)&Bs[d][hb][cn * 64 + ((((kh << 2) | kg) ^ (cn & 7)) << 3)];
      }
    if (tt + 1 < ns) STG_AH(nd, 1, tt + 1);
    __builtin_amdgcn_s_barrier();
    asm volatile("s_waitcnt lgkmcnt(0)");
    __builtin_amdgcn_s_setprio(1);
#pragma unroll
    for (int mi = 0; mi < MQ; ++mi)
#pragma unroll
      for (int ni = 0; ni < 2; ++ni)
#pragma unroll
        for (int kh = 0; kh < 2; ++kh)
          acc[mi][2 + ni] = __builtin_amdgcn_mfma_f32_16x16x32_bf16(af[mi][kh], bf[1][ni][kh], acc[mi][2 + ni], 0, 0, 0);
    __builtin_amdgcn_s_setprio(0);
    __builtin_amdgcn_s_barrier();

    // ---- phase 2: Q(1,1) ----
#pragma unroll
    for (int mi = 0; mi < MQ; ++mi)
#pragma unroll
      for (int kh = 0; kh < 2; ++kh){
        const int rh = MQ * 16 + mi * 16 + fr;
        af[mi][kh] = *(const bfrag*)&As[d][ha][rh * 64 + ((((kh << 2) | kg) ^ (rh & 7)) << 3)];
      }
    if (tt + 2 < ns) STG_BH(d, 0, tt + 2);
    __builtin_amdgcn_s_barrier();
    asm volatile("s_waitcnt lgkmcnt(0)");
    __builtin_amdgcn_s_setprio(1);
#pragma unroll
    for (int mi = 0; mi < MQ; ++mi)
#pragma unroll
      for (int ni = 0; ni < 2; ++ni)
#pragma unroll
        for (int kh = 0; kh < 2; ++kh)
          acc[MQ + mi][2 + ni] = __builtin_amdgcn_mfma_f32_16x16x32_bf16(af[mi][kh], bf[1][ni][kh], acc[MQ + mi][2 + ni], 0, 0, 0);
    __builtin_amdgcn_s_setprio(0);
    __builtin_amdgcn_s_barrier();

    // ---- phase 3: Q(1,0) ----
    if (tt + 2 < ns) STG_AH(d, 0, tt + 2);
    __builtin_amdgcn_s_barrier();
    __builtin_amdgcn_s_setprio(1);
#pragma unroll
    for (int mi = 0; mi < MQ; ++mi)
#pragma unroll
      for (int ni = 0; ni < 2; ++ni)
#pragma unroll
        for (int kh = 0; kh < 2; ++kh)
          acc[MQ + mi][ni] = __builtin_amdgcn_mfma_f32_16x16x32_bf16(af[mi][kh], bf[0][ni][kh], acc[MQ + mi][ni], 0, 0, 0);
    __builtin_amdgcn_s_setprio(0);
    if (tt + 2 < ns)      asm volatile("s_waitcnt vmcnt(%0)" :: "i"(2 + ALD) : "memory");
    else if (tt + 1 < ns) asm volatile("s_waitcnt vmcnt(0)" ::: "memory");
    if (tt + 1 < ns) __builtin_amdgcn_s_barrier();
  }

  // ---------------- epilogue ----------------
  if constexpr (EPI == 3){
    const int base = bn + wn;
    if (base < 16384){
      const int colb = base >> 1;
#pragma unroll
      for (int mh = 0; mh < 2; ++mh)
#pragma unroll
        for (int mi = 0; mi < MQ; ++mi){
          const int row0 = bm + ha * HR + mh * (HR / 2) + mi * 16 + kg * 4;
#pragma unroll
          for (int p = 0; p < 2; ++p){
            f4 g = acc[mh * MQ + mi][2 * p];
            f4 u = acc[mh * MQ + mi][2 * p + 1];
#pragma unroll
            for (int r = 0; r < 4; ++r)
              ((unsigned short*)Cp)[(long long)(row0 + r) * 8192 + colb + p * 16 + fr]
                = f2bf(silu_f(g[r]) * u[r]);
          }
        }
    } else if (base < 16896){
      const int cb2 = base - 16384;
#pragma unroll
      for (int mh = 0; mh < 2; ++mh)
#pragma unroll
        for (int mi = 0; mi < MQ; ++mi){
          const int row0 = bm + ha * HR + mh * (HR / 2) + mi * 16 + kg * 4;
#pragma unroll
          for (int nf = 0; nf < 4; ++nf){
            f4 v = acc[mh * MQ + mi][nf];
#pragma unroll
            for (int r = 0; r < 4; ++r)
              ((unsigned short*)Cp2)[(long long)(row0 + r) * 512 + cb2 + nf * 16 + fr] = f2bf(v[r]);
          }
        }
    } else {
      const int cb3 = base - 16896;
#pragma unroll
      for (int mh = 0; mh < 2; ++mh)
#pragma unroll
        for (int mi = 0; mi < MQ; ++mi){
          const int row0 = bm + ha * HR + mh * (HR / 2) + mi * 16 + kg * 4;
#pragma unroll
          for (int nf = 0; nf < 4; ++nf){
            const int col = cb3 + nf * 16 + fr;
            f4 v = acc[mh * MQ + mi][nf];
            if (col < 64){
#pragma unroll
              for (int r = 0; r < 4; ++r)
                ((float*)Cp3)[(long long)(row0 + r) * 64 + col] = v[r];
            }
          }
        }
    }
    return;
  }
#pragma unroll
  for (int mh = 0; mh < 2; ++mh)
#pragma unroll
    for (int mi = 0; mi < MQ; ++mi){
      const int row0 = bm + ha * HR + mh * (HR / 2) + mi * 16 + kg * 4;
#pragma unroll
      for (int nf = 0; nf < 4; ++nf){
        const int col = bn + wn + nf * 16 + fr;
        f4 v = acc[mh * MQ + mi][nf];
#pragma unroll
        for (int r = 0; r < 4; ++r){
          const long long off = (long long)(row0 + r) * N + col;
          if (EPI == 0)      ((unsigned short*)Cp)[off] = f2bf(v[r]);
          else if (EPI == 1) ((float*)Cp)[off] = v[r];
          else               ((float*)Cp)[off] = (v[r] + addin[off]) * 0.5f;
        }
      }
    }
#undef STG_AH
#undef STG_BH
}

// ---------------- generic 128x128 C = A @ B^T GEMM (bounds-checked) --------
// EPI: 0 = bf16 out; 3 = 16-col-interleaved silu(g)*u pairs -> bf16, ld N/2
template<int EPI>
__global__ __launch_bounds__(256) void gemm_bt(
    const unsigned short* __restrict__ A, const unsigned short* __restrict__ B,
    void* __restrict__ Cp, const float* __restrict__ addin,
    int M, int N, int K, long long sA, long long sB, long long sC)
{
  __shared__ unsigned short As[128*32];
  __shared__ unsigned short Bs[128*32];
  A += (long long)blockIdx.z * sA;
  B += (long long)blockIdx.z * sB;
  const long long cbase = (long long)blockIdx.z * sC;
  const int bm = blockIdx.y * 128, bn = blockIdx.x * 128;
  const int t = threadIdx.x, wave = t >> 6, lane = t & 63;
  const int wm = (wave >> 1) * 64, wn = (wave & 1) * 64;
  const int fr = lane & 15, kg = lane >> 4;

  f4 acc[4][4];
#pragma unroll
  for (int m = 0; m < 4; ++m)
#pragma unroll
    for (int n = 0; n < 4; ++n)
      acc[m][n] = f4{0.f, 0.f, 0.f, 0.f};

  const int i0 = t, i1 = 256 + t;
  int ar0 = bm + (i0 >> 2); if (ar0 > M - 1) ar0 = M - 1;
  int ar1 = bm + (i1 >> 2); if (ar1 > M - 1) ar1 = M - 1;
  int br0 = bn + (i0 >> 2); if (br0 > N - 1) br0 = N - 1;
  int br1 = bn + (i1 >> 2); if (br1 > N - 1) br1 = N - 1;
  const unsigned short* ap0 = A + (long long)ar0 * K + (i0 & 3) * 8;
  const unsigned short* ap1 = A + (long long)ar1 * K + (i1 & 3) * 8;
  const unsigned short* bp0 = B + (long long)br0 * K + (i0 & 3) * 8;
  const unsigned short* bp1 = B + (long long)br1 * K + (i1 & 3) * 8;
  unsigned short* da0 = As + wave * 512;
  unsigned short* da1 = As + 2048 + wave * 512;
  unsigned short* db0 = Bs + wave * 512;
  unsigned short* db1 = Bs + 2048 + wave * 512;

  for (int k0 = 0; k0 < K; k0 += 32){
    gl_lds16(ap0, da0);
    gl_lds16(ap1, da1);
    gl_lds16(bp0, db0);
    gl_lds16(bp1, db1);
    ap0 += 32; ap1 += 32; bp0 += 32; bp1 += 32;
    __syncthreads();
    bfrag af[4], bfv[4];
#pragma unroll
    for (int m = 0; m < 4; ++m) af[m] = *(const bfrag*)&As[(wm + m*16 + fr)*32 + kg*8];
#pragma unroll
    for (int n = 0; n < 4; ++n) bfv[n] = *(const bfrag*)&Bs[(wn + n*16 + fr)*32 + kg*8];
#pragma unroll
    for (int m = 0; m < 4; ++m)
#pragma unroll
      for (int n = 0; n < 4; ++n)
        acc[m][n] = __builtin_amdgcn_mfma_f32_16x16x32_bf16(af[m], bfv[n], acc[m][n], 0, 0, 0);
    __syncthreads();
  }

  if constexpr (EPI == 3){
    const int colb = (bn + wn) >> 1;
    const int ldo = N >> 1;
#pragma unroll
    for (int m = 0; m < 4; ++m){
      const int row0 = bm + wm + m*16 + kg*4;
#pragma unroll
      for (int p = 0; p < 2; ++p){
        f4 g = acc[m][2*p], u = acc[m][2*p+1];
#pragma unroll
        for (int r = 0; r < 4; ++r){
          const int row = row0 + r;
          if (row < M)
            ((unsigned short*)Cp)[cbase + (long long)row * ldo + colb + p*16 + fr]
              = f2bf(silu_f(g[r]) * u[r]);
        }
      }
    }
    return;
  }
#pragma unroll
  for (int m = 0; m < 4; ++m){
    const int row0 = bm + wm + m*16 + kg*4;
#pragma unroll
    for (int n = 0; n < 4; ++n){
      const int col = bn + wn + n*16 + fr;
      if (col < N){
        f4 v = acc[m][n];
#pragma unroll
        for (int r = 0; r < 4; ++r){
          const int row = row0 + r;
          if (row < M){
            const long long off = cbase + (long long)row * N + col;
            ((unsigned short*)Cp)[off] = f2bf(v[r]);
          }
        }
      }
    }
  }
}

// ---------------- f32 -> bf16 convert (vectorized) ----------------
__global__ void cvt_bf16(const float* __restrict__ in, unsigned short* __restrict__ out,
                         long long n4)
{
  long long i = (long long)blockIdx.x * 256 + threadIdx.x;
  if (i >= n4) return;
  float4 v = ((const float4*)in)[i];
  us4 o; o[0] = f2bf(v.x); o[1] = f2bf(v.y); o[2] = f2bf(v.z); o[3] = f2bf(v.w);
  ((us4*)out)[i] = o;
}

// ---------------- f32 -> bf16 with 16-row interleave (gate/up pairing) -----
// src row j (8192 x 2048) -> dst row ((j>>4)<<5) | (hi<<4) | (j&15)
__global__ void cvt_rowmap(const float* __restrict__ in, unsigned short* __restrict__ out,
                           int hi)
{
  const long long idx = (long long)blockIdx.x * 256 + threadIdx.x;   // 4194304 f4
  const int row = (int)(idx >> 9);
  const int c4 = ((int)idx & 511) << 2;
  const int orow = ((row >> 4) << 5) | (hi << 4) | (row & 15);
  float4 v = *(const float4*)(in + (long long)row * 2048 + c4);
  us4 o; o[0] = f2bf(v.x); o[1] = f2bf(v.y); o[2] = f2bf(v.z); o[3] = f2bf(v.w);
  *(us4*)(out + (long long)orow * 2048 + c4) = o;
}

// ---------------- [z][R][C] f32 -> [z][C][R] bf16 (MODE1: interleave rows) --
template<int MODE>
__global__ __launch_bounds__(256) void transpose_cvt(const float* __restrict__ in,
    unsigned short* __restrict__ out, int R, int C)
{
  __shared__ float tile[32][33];
  const long long z = blockIdx.z;
  const float* ip = in + z * (long long)R * C;
  unsigned short* op = out + z * (long long)R * C;
  const int r0 = blockIdx.y * 32, c0 = blockIdx.x * 32;
  const int t = threadIdx.x;
  const int lr = t >> 3, lc = (t & 7) * 4;
  float4 v = *(const float4*)(ip + (long long)(r0 + lr) * C + c0 + lc);
  tile[lr][lc+0] = v.x; tile[lr][lc+1] = v.y; tile[lr][lc+2] = v.z; tile[lr][lc+3] = v.w;
  __syncthreads();
  const int oc = t >> 3, orr = (t & 7) * 4;
  us4 o;
  o[0] = f2bf(tile[orr+0][oc]); o[1] = f2bf(tile[orr+1][oc]);
  o[2] = f2bf(tile[orr+2][oc]); o[3] = f2bf(tile[orr+3][oc]);
  int c = c0 + oc;
  int orow;
  if (MODE == 1)
    orow = (c < 1536) ? (((c >> 4) << 5) | (c & 15))
                      : ((((c - 1536) >> 4) << 5) | 16 | ((c - 1536) & 15));
  else
    orow = c;
  *(us4*)(op + (long long)orow * R + r0 + orr) = o;
}

// ---------------- router: top-4, softmax gating, z-loss ----------------
__global__ void router_topk(const float* __restrict__ logits, int* __restrict__ topk,
                            float* __restrict__ gating, float* __restrict__ zout)
{
  const int t = threadIdx.x, w = t >> 6, lane = t & 63;
  const int n = blockIdx.x * 4 + w;
  const float lg = logits[(long long)n * 64 + lane];
  float z = lg * lg;
#pragma unroll
  for (int off = 32; off; off >>= 1) z += __shfl_xor(z, off);
  __shared__ float zs[4];
  if (lane == 0) zs[w] = z;
  __syncthreads();
  if (t == 0) atomicAdd(zout, (zs[0]+zs[1]+zs[2]+zs[3]) * (0.0001f / 262144.0f));

  float cur = lg;
  float tl[4]; int ti[4];
#pragma unroll
  for (int k = 0; k < 4; ++k){
    float s = cur; int si = lane;
#pragma unroll
    for (int off = 32; off; off >>= 1){
      float so = __shfl_xor(s, off); int io = __shfl_xor(si, off);
      if (so > s || (so == s && io < si)){ s = so; si = io; }
    }
    tl[k] = s; ti[k] = si;
    if (lane == si) cur = -3.0e38f;
  }
  if (lane == 0){
    const float m0 = tl[0];
    const float e0 = __expf(tl[0]-m0), e1 = __expf(tl[1]-m0),
                e2 = __expf(tl[2]-m0), e3 = __expf(tl[3]-m0);
    const float inv = 1.0f / (e0 + e1 + e2 + e3);
    topk[n*4+0] = ti[0]; topk[n*4+1] = ti[1]; topk[n*4+2] = ti[2]; topk[n*4+3] = ti[3];
    gating[n*4+0] = e0*inv; gating[n*4+1] = e1*inv; gating[n*4+2] = e2*inv; gating[n*4+3] = e3*inv;
  }
}

// ---------------- deterministic per-expert rank scan ----------------
__global__ void scan_route(const int* __restrict__ topk, int* __restrict__ gm,
                           int* __restrict__ rev, int* __restrict__ counts)
{
  const int e = blockIdx.x;
  const int t = threadIdx.x, w = t >> 6, lane = t & 63;
  __shared__ int wtot[4];
  int running = 0;
  for (int c = 0; c < 16384; c += 256){
    const int j = c + t;
    const bool p = (topk[j] == e);
    const unsigned long long m = __ballot(p);
    const int prefix = __popcll(m & ((1ull << lane) - 1ull));
    if (lane == 0) wtot[w] = __popcll(m);
    __syncthreads();
    int woff = 0;
#pragma unroll
    for (int i = 0; i < 4; ++i){ if (i < w) woff += wtot[i]; }
    const int btot = wtot[0] + wtot[1] + wtot[2] + wtot[3];
    if (p){
      const int rank = running + woff + prefix;
      gm[j] = (rank < MAXLD) ? (e * MAXLD + rank) : NSLOT;
      if (rank < MAXLD) rev[e * MAXLD + rank] = j >> 2;
    }
    running += btot;
    __syncthreads();
  }
  if (t == 0) counts[e] = running;
}

// ---------------- gather down-projected tokens into expert slots ----------------
__global__ void gather_pad(const unsigned short* __restrict__ down, const int* __restrict__ rev,
                           const int* __restrict__ counts, unsigned short* __restrict__ pad)
{
  const int idx = blockIdx.x * 256 + threadIdx.x;
  const int s = idx >> 6, c8 = (idx & 63) * 8;
  const int e = s / MAXLD;
  const int r = s - e * MAXLD;
  int cnt = counts[e]; if (cnt > MAXLD) cnt = MAXLD;
  us8 v = {0,0,0,0,0,0,0,0};
  if (r < cnt){
    const int tok = rev[s];
    v = *(const us8*)(down + (long long)tok * 512 + c8);
  }
  *(us8*)(pad + (long long)s * 512 + c8) = v;
}

// ---------------- gating-weighted combine ----------------
__global__ void combine_moe(const unsigned short* __restrict__ po, const int* __restrict__ gm,
                            const float* __restrict__ gating, unsigned short* __restrict__ routed)
{
  const int idx = blockIdx.x * 256 + threadIdx.x;
  const int n = idx >> 6, c8 = (idx & 63) * 8;
  float acc[8] = {0,0,0,0,0,0,0,0};
#pragma unroll
  for (int k = 0; k < 4; ++k){
    const int slot = gm[n*4 + k];
    if (slot < NSLOT){
      const float gw = gating[n*4 + k];
      us8 v = *(const us8*)(po + (long long)slot * 512 + c8);
#pragma unroll
      for (int j = 0; j < 8; ++j) acc[j] += gw * bf2f(v[j]);
    }
  }
  us8 o;
#pragma unroll
  for (int j = 0; j < 8; ++j) o[j] = f2bf(acc[j]);
  *(us8*)(routed + (long long)n * 512 + c8) = o;
}

// =====================================================================
extern "C" void kernel_launch(void* const* d_in, const int* in_sizes, int n_in,
                              void* d_out, int out_size, void* d_ws, size_t ws_size,
                              hipStream_t stream)
{
  const float* x      = (const float*)d_in[0];
  const float* rw     = (const float*)d_in[1];
  const float* gate_w = (const float*)d_in[2];
  const float* up_w   = (const float*)d_in[3];
  const float* down_w = (const float*)d_in[4];
  const float* w_down = (const float*)d_in[5];
  const float* w_up   = (const float*)d_in[6];
  const float* w12    = (const float*)d_in[7];
  const float* w3     = (const float*)d_in[8];
  float* out = (float*)d_out;

  char* ws = (char*)d_ws;
  unsigned short* HBF   = (unsigned short*)(ws + 0ull);            // 16.78 MB
  unsigned short* BBIG  = (unsigned short*)(ws + 16777216ull);     // 70.25 MB [17152][2048]
  unsigned short* DWB   = (unsigned short*)(ws + 87031808ull);     // 33.55 MB
  unsigned short* WUB   = (unsigned short*)(ws + 120586240ull);    // 2.10 MB
  unsigned short* W12I  = (unsigned short*)(ws + 122683392ull);    // 201.3 MB interleaved
  unsigned short* W3T   = (unsigned short*)(ws + 324009984ull);    // 100.7 MB
  float*          LOGIT = (float*)(ws + 424673280ull);             // 1.05 MB
  int*            TOPKI = (int*)(ws + 425721856ull);
  float*          GATE4 = (float*)(ws + 425787392ull);
  int*            GM    = (int*)(ws + 425852928ull);
  int*            CNT   = (int*)(ws + 425918464ull);
  int*            REV   = (int*)(ws + 425919488ull);
  unsigned short* ACTS  = (unsigned short*)(ws + 426000384ull);    // 67.1 MB [4096][8192]
  unsigned short* AEXP  = (unsigned short*)(ws + 493109248ull);    // 59.8 MB [E][304][1536]
  float*          SHRD  = (float*)(ws + 552878080ull);             // 33.55 MB
  unsigned short* DNB   = (unsigned short*)(ws + 586432512ull);    // 4.19 MB
  unsigned short* PAD   = (unsigned short*)(ws + 590626816ull);    // 19.92 MB
  unsigned short* PO    = (unsigned short*)(ws + 610549760ull);    // 19.92 MB
  unsigned short* RTD   = (unsigned short*)(ws + 630472704ull);    // 4.19 MB (end ~634.7MB)

  // z-loss slot + zero-pad rows of BBIG (router pad 16960..17151)
  hipMemsetAsync((char*)d_out + 8388608ull * 4, 0, 4, stream);
  hipMemsetAsync(BBIG + 16960ull * 2048, 0, 192ull * 2048 * 2, stream);

  // bf16 conversions / layout builds
  cvt_bf16<<<8192,  256, 0, stream>>>(x, HBF, 2097152);
  cvt_rowmap<<<16384, 256, 0, stream>>>(gate_w, BBIG, 0);
  cvt_rowmap<<<16384, 256, 0, stream>>>(up_w,   BBIG, 1);
  cvt_bf16<<<1024,  256, 0, stream>>>(w_down, BBIG + 16384ull * 2048, 262144);
  cvt_bf16<<<128,   256, 0, stream>>>(rw,     BBIG + 16896ull * 2048, 32768);
  cvt_bf16<<<16384, 256, 0, stream>>>(down_w, DWB, 4194304);
  cvt_bf16<<<1024,  256, 0, stream>>>(w_up,   WUB, 262144);
  transpose_cvt<1><<<dim3(96,16,64), 256, 0, stream>>>(w12, W12I, 512, 3072);
  transpose_cvt<0><<<dim3(16,48,64), 256, 0, stream>>>(w3,  W3T,  1536, 512);

  // MEGA GEMM: gate+up (fused silu) + w_down + router logits in one pass
  gemm2<256,3><<<dim3(67,16), 512, 0, stream>>>(HBF, BBIG, ACTS, nullptr,
                                                4096, 17152, 2048, DNB, LOGIT);

  // routing
  router_topk<<<1024, 256, 0, stream>>>(LOGIT, TOPKI, GATE4, out + 8388608);
  scan_route<<<64, 256, 0, stream>>>(TOPKI, GM, REV, CNT);
  gather_pad<<<4864, 256, 0, stream>>>(DNB, REV, CNT, PAD);

  // expert MLPs (silu fused into GEMM1 epilogue via interleaved W12I)
  gemm_bt<3><<<dim3(24,3,64), 256, 0, stream>>>(PAD, W12I, AEXP, nullptr,
                                                304, 3072, 512, 155648, 1572864, 466944);
  gemm_bt<0><<<dim3(4,3,64), 256, 0, stream>>>(AEXP, W3T, PO, nullptr,
                                               304, 512, 1536, 466944, 786432, 155648);
  combine_moe<<<1024, 256, 0, stream>>>(PO, GM, GATE4, RTD);

  // shared down-proj and final combine
  gemm2<128,1><<<dim3(8,32), 512, 0, stream>>>(ACTS, DWB, SHRD, nullptr,
                                               4096, 2048, 8192, nullptr, nullptr);
  gemm2<128,2><<<dim3(8,32), 512, 0, stream>>>(RTD, WUB, out, SHRD,
                                               4096, 2048, 512, nullptr, nullptr);
}

// Round 7
// 1115.109 us; speedup vs baseline: 1.0840x; 1.0079x over previous
//
#include <hip/hip_runtime.h>

#define DEV __device__ __forceinline__

typedef __attribute__((ext_vector_type(4))) float f4;
typedef __attribute__((ext_vector_type(8))) __bf16 bfrag;
typedef __attribute__((ext_vector_type(4))) unsigned short us4;
typedef __attribute__((ext_vector_type(8))) unsigned short us8;

// problem constants
#define NTOK   4096
#define DMODEL 2048
#define NEXP   64
#define MAXLD  304
#define NSLOT  19456   // 64*304

DEV unsigned short f2bf(float f){
  union { float f; unsigned int i; } u; u.f = f;
  unsigned int r = u.i + 0x7fffu + ((u.i >> 16) & 1u);
  return (unsigned short)(r >> 16);
}
DEV float bf2f(unsigned short b){
  union { unsigned int i; float f; } u; u.i = ((unsigned int)b) << 16;
  return u.f;
}
DEV float silu_f(float g){ return g / (1.0f + __expf(-g)); }

DEV void gl_lds16(const unsigned short* g, unsigned short* l){
  __builtin_amdgcn_global_load_lds(
      (const __attribute__((address_space(1))) void*)g,
      (__attribute__((address_space(3))) void*)l, 16, 0, 0);
}

// ============== 4-phase/K-step GEMM: C = A @ B^T =============
// A: rows use lda (>=K), B: ldb. blockIdx.z adds element strides sA/sB/sC
// (grouped experts or split-K). Staging rows clamp to M-1; epilogue masks.
// XCD swizzle auto-applies when (gridDim.x*gridDim.y)%8==0.
// EPI: 0 = bf16 out (ld N), 1 = f32 out (ld N),
//      2 = f32 out = (acc + add0 + add1)*0.5 (ld N),
//      3 = MEGA: cols[0,16384) interleaved (g,u)->silu->bf16 ACTS ld 8192;
//          [16384,16896) bf16 -> Cp2 ld 512; [16896,16960) f32 -> Cp3 ld 64.
//      4 = interleaved (g,u)->silu->bf16, ld N/2, honors sC & M-bounds.
template<int BM, int EPI>
__global__ __launch_bounds__(512, 1) void gemm2(
    const unsigned short* __restrict__ A, const unsigned short* __restrict__ B,
    void* __restrict__ Cp, const float* __restrict__ add0, const float* __restrict__ add1,
    int M, int N, int K, int lda, int ldb,
    long long sA, long long sB, long long sC,
    void* __restrict__ Cp2, void* __restrict__ Cp3)
{
  constexpr int ALD = BM / 128;   // gl_lds per thread per A-half-tile (2 or 1)
  constexpr int MQ  = BM / 64;    // m-frags per quadrant (4 or 2)
  constexpr int HR  = BM / 2;     // rows per A half
  __shared__ unsigned short As[2][2][HR * 64];
  __shared__ unsigned short Bs[2][2][128 * 64];

  A += (long long)blockIdx.z * sA;
  B += (long long)blockIdx.z * sB;
  const long long cbase = (long long)blockIdx.z * sC;

  const int nwg = gridDim.x * gridDim.y;
  int bid = blockIdx.y * gridDim.x + blockIdx.x;
  if ((nwg & 7) == 0) bid = (bid & 7) * (nwg >> 3) + (bid >> 3);
  const int bx = bid % gridDim.x, by = bid / gridDim.x;
  const int bm = by * BM, bn = bx * 256;

  const int t = threadIdx.x, lane = t & 63, wave = t >> 6;
  const int ha = wave >> 2;          // this wave's A half
  const int wn = (wave & 3) * 64;
  const int hb = wn >> 7;            // this wave's B half
  const int cb = wn & 127;           // col base within B half
  const int fr = lane & 15, kg = lane >> 4;

  const int r0 = t >> 3;
  const int s0 = (t & 7) ^ (r0 & 7);

#define STG_AH(d_, h_, s_) do {                                                          \
    int rA0 = bm + (h_) * HR + r0; if (rA0 > M - 1) rA0 = M - 1;                         \
    gl_lds16(A + (long long)rA0 * lda + (long long)(s_) * 64 + s0 * 8,                   \
             &As[d_][h_][(wave * 64) * 8]);                                              \
    if (ALD == 2){                                                                       \
      int rA1 = bm + (h_) * HR + r0 + 64; if (rA1 > M - 1) rA1 = M - 1;                  \
      gl_lds16(A + (long long)rA1 * lda + (long long)(s_) * 64 + s0 * 8,                 \
               &As[d_][h_][(512 + wave * 64) * 8]);                                      \
    }                                                                                    \
  } while (0)
#define STG_BH(d_, h_, s_) do {                                                          \
    gl_lds16(B + (long long)(bn + (h_) * 128 + r0) * ldb + (long long)(s_) * 64 + s0 * 8,\
             &Bs[d_][h_][(wave * 64) * 8]);                                              \
    gl_lds16(B + (long long)(bn + (h_) * 128 + r0 + 64) * ldb + (long long)(s_) * 64 + s0 * 8, \
             &Bs[d_][h_][(512 + wave * 64) * 8]);                                        \
  } while (0)

  f4 acc[2 * MQ][4];
#pragma unroll
  for (int m = 0; m < 2 * MQ; ++m)
#pragma unroll
    for (int n = 0; n < 4; ++n) acc[m][n] = f4{0.f, 0.f, 0.f, 0.f};

  const int ns = K >> 6;   // all call sites: ns >= 8

  STG_BH(0, 0, 0); STG_AH(0, 0, 0); STG_BH(0, 1, 0); STG_AH(0, 1, 0);
  STG_BH(1, 0, 1); STG_AH(1, 0, 1);
  asm volatile("s_waitcnt vmcnt(%0)" :: "i"(2 + ALD) : "memory");
  __builtin_amdgcn_s_barrier();

  for (int tt = 0; tt < ns; ++tt){
    const int d = tt & 1, nd = d ^ 1;
    bfrag af[MQ][2], bf[2][2][2];

    // ---- phase 0: Q(0,0) ----
#pragma unroll
    for (int ni = 0; ni < 2; ++ni)
#pragma unroll
      for (int kh = 0; kh < 2; ++kh){
        const int cn = cb + ni * 16 + fr;
        bf[0][ni][kh] = *(const bfrag*)&Bs[d][hb][cn * 64 + ((((kh << 2) | kg) ^ (cn & 7)) << 3)];
      }
#pragma unroll
    for (int mi = 0; mi < MQ; ++mi)
#pragma unroll
      for (int kh = 0; kh < 2; ++kh){
        const int rh = mi * 16 + fr;
        af[mi][kh] = *(const bfrag*)&As[d][ha][rh * 64 + ((((kh << 2) | kg) ^ (rh & 7)) << 3)];
      }
    if (tt + 1 < ns) STG_BH(nd, 1, tt + 1);
    if constexpr (BM == 256) asm volatile("s_waitcnt lgkmcnt(8)");
    else                     asm volatile("s_waitcnt lgkmcnt(4)");
    __builtin_amdgcn_s_barrier();
    asm volatile("s_waitcnt lgkmcnt(0)");
    __builtin_amdgcn_s_setprio(1);
#pragma unroll
    for (int mi = 0; mi < MQ; ++mi)
#pragma unroll
      for (int ni = 0; ni < 2; ++ni)
#pragma unroll
        for (int kh = 0; kh < 2; ++kh)
          acc[mi][ni] = __builtin_amdgcn_mfma_f32_16x16x32_bf16(af[mi][kh], bf[0][ni][kh], acc[mi][ni], 0, 0, 0);
    __builtin_amdgcn_s_setprio(0);
    __builtin_amdgcn_s_barrier();

    // ---- phase 1: Q(0,1) ----
#pragma unroll
    for (int ni = 0; ni < 2; ++ni)
#pragma unroll
      for (int kh = 0; kh < 2; ++kh){
        const int cn = cb + 32 + ni * 16 + fr;
        bf[1][ni][kh] = *(const bfrag*)&Bs[d][hb][cn * 64 + ((((kh << 2) | kg) ^ (cn & 7)) << 3)];
      }
    if (tt + 1 < ns) STG_AH(nd, 1, tt + 1);
    __builtin_amdgcn_s_barrier();
    asm volatile("s_waitcnt lgkmcnt(0)");
    __builtin_amdgcn_s_setprio(1);
#pragma unroll
    for (int mi = 0; mi < MQ; ++mi)
#pragma unroll
      for (int ni = 0; ni < 2; ++ni)
#pragma unroll
        for (int kh = 0; kh < 2; ++kh)
          acc[mi][2 + ni] = __builtin_amdgcn_mfma_f32_16x16x32_bf16(af[mi][kh], bf[1][ni][kh], acc[mi][2 + ni], 0, 0, 0);
    __builtin_amdgcn_s_setprio(0);
    __builtin_amdgcn_s_barrier();

    // ---- phase 2: Q(1,1) ----
#pragma unroll
    for (int mi = 0; mi < MQ; ++mi)
#pragma unroll
      for (int kh = 0; kh < 2; ++kh){
        const int rh = MQ * 16 + mi * 16 + fr;
        af[mi][kh] = *(const bfrag*)&As[d][ha][rh * 64 + ((((kh << 2) | kg) ^ (rh & 7)) << 3)];
      }
    if (tt + 2 < ns) STG_BH(d, 0, tt + 2);
    __builtin_amdgcn_s_barrier();
    asm volatile("s_waitcnt lgkmcnt(0)");
    __builtin_amdgcn_s_setprio(1);
#pragma unroll
    for (int mi = 0; mi < MQ; ++mi)
#pragma unroll
      for (int ni = 0; ni < 2; ++ni)
#pragma unroll
        for (int kh = 0; kh < 2; ++kh)
          acc[MQ + mi][2 + ni] = __builtin_amdgcn_mfma_f32_16x16x32_bf16(af[mi][kh], bf[1][ni][kh], acc[MQ + mi][2 + ni], 0, 0, 0);
    __builtin_amdgcn_s_setprio(0);
    __builtin_amdgcn_s_barrier();

    // ---- phase 3: Q(1,0) ----
    if (tt + 2 < ns) STG_AH(d, 0, tt + 2);
    __builtin_amdgcn_s_barrier();
    __builtin_amdgcn_s_setprio(1);
#pragma unroll
    for (int mi = 0; mi < MQ; ++mi)
#pragma unroll
      for (int ni = 0; ni < 2; ++ni)
#pragma unroll
        for (int kh = 0; kh < 2; ++kh)
          acc[MQ + mi][ni] = __builtin_amdgcn_mfma_f32_16x16x32_bf16(af[mi][kh], bf[0][ni][kh], acc[MQ + mi][ni], 0, 0, 0);
    __builtin_amdgcn_s_setprio(0);
    if (tt + 2 < ns)      asm volatile("s_waitcnt vmcnt(%0)" :: "i"(2 + ALD) : "memory");
    else if (tt + 1 < ns) asm volatile("s_waitcnt vmcnt(0)" ::: "memory");
    if (tt + 1 < ns) __builtin_amdgcn_s_barrier();
  }

  // ---------------- epilogue ----------------
  if constexpr (EPI == 3){
    const int base = bn + wn;
    if (base < 16384){
      const int colb = base >> 1;
#pragma unroll
      for (int mh = 0; mh < 2; ++mh)
#pragma unroll
        for (int mi = 0; mi < MQ; ++mi){
          const int row0 = bm + ha * HR + mh * (HR / 2) + mi * 16 + kg * 4;
#pragma unroll
          for (int p = 0; p < 2; ++p){
            f4 g = acc[mh * MQ + mi][2 * p];
            f4 u = acc[mh * MQ + mi][2 * p + 1];
#pragma unroll
            for (int r = 0; r < 4; ++r)
              ((unsigned short*)Cp)[(long long)(row0 + r) * 8192 + colb + p * 16 + fr]
                = f2bf(silu_f(g[r]) * u[r]);
          }
        }
    } else if (base < 16896){
      const int cb2 = base - 16384;
#pragma unroll
      for (int mh = 0; mh < 2; ++mh)
#pragma unroll
        for (int mi = 0; mi < MQ; ++mi){
          const int row0 = bm + ha * HR + mh * (HR / 2) + mi * 16 + kg * 4;
#pragma unroll
          for (int nf = 0; nf < 4; ++nf){
            f4 v = acc[mh * MQ + mi][nf];
#pragma unroll
            for (int r = 0; r < 4; ++r)
              ((unsigned short*)Cp2)[(long long)(row0 + r) * 512 + cb2 + nf * 16 + fr] = f2bf(v[r]);
          }
        }
    } else {
      const int cb3 = base - 16896;
#pragma unroll
      for (int mh = 0; mh < 2; ++mh)
#pragma unroll
        for (int mi = 0; mi < MQ; ++mi){
          const int row0 = bm + ha * HR + mh * (HR / 2) + mi * 16 + kg * 4;
#pragma unroll
          for (int nf = 0; nf < 4; ++nf){
            const int col = cb3 + nf * 16 + fr;
            f4 v = acc[mh * MQ + mi][nf];
            if (col < 64){
#pragma unroll
              for (int r = 0; r < 4; ++r)
                ((float*)Cp3)[(long long)(row0 + r) * 64 + col] = v[r];
            }
          }
        }
    }
    return;
  }
  if constexpr (EPI == 4){
    const int colb = (bn + wn) >> 1;
    const int ldo = N >> 1;
#pragma unroll
    for (int mh = 0; mh < 2; ++mh)
#pragma unroll
      for (int mi = 0; mi < MQ; ++mi){
        const int row0 = bm + ha * HR + mh * (HR / 2) + mi * 16 + kg * 4;
#pragma unroll
        for (int p = 0; p < 2; ++p){
          f4 g = acc[mh * MQ + mi][2 * p];
          f4 u = acc[mh * MQ + mi][2 * p + 1];
#pragma unroll
          for (int r = 0; r < 4; ++r){
            const int row = row0 + r;
            if (row < M)
              ((unsigned short*)Cp)[cbase + (long long)row * ldo + colb + p * 16 + fr]
                = f2bf(silu_f(g[r]) * u[r]);
          }
        }
      }
    return;
  }
#pragma unroll
  for (int mh = 0; mh < 2; ++mh)
#pragma unroll
    for (int mi = 0; mi < MQ; ++mi){
      const int row0 = bm + ha * HR + mh * (HR / 2) + mi * 16 + kg * 4;
#pragma unroll
      for (int nf = 0; nf < 4; ++nf){
        const int col = bn + wn + nf * 16 + fr;
        f4 v = acc[mh * MQ + mi][nf];
#pragma unroll
        for (int r = 0; r < 4; ++r){
          const int row = row0 + r;
          if (row < M){
            const long long off = cbase + (long long)row * N + col;
            if (EPI == 0)      ((unsigned short*)Cp)[off] = f2bf(v[r]);
            else if (EPI == 1) ((float*)Cp)[off] = v[r];
            else               ((float*)Cp)[off] = (v[r] + add0[off] + add1[off]) * 0.5f;
          }
        }
      }
    }
#undef STG_AH
#undef STG_BH
}

// ---------------- f32 -> bf16 convert (vectorized) ----------------
__global__ void cvt_bf16(const float* __restrict__ in, unsigned short* __restrict__ out,
                         long long n4)
{
  long long i = (long long)blockIdx.x * 256 + threadIdx.x;
  if (i >= n4) return;
  float4 v = ((const float4*)in)[i];
  us4 o; o[0] = f2bf(v.x); o[1] = f2bf(v.y); o[2] = f2bf(v.z); o[3] = f2bf(v.w);
  ((us4*)out)[i] = o;
}

// ---------------- f32 -> bf16 with 16-row interleave (gate/up pairing) -----
__global__ void cvt_rowmap(const float* __restrict__ in, unsigned short* __restrict__ out,
                           int hi)
{
  const long long idx = (long long)blockIdx.x * 256 + threadIdx.x;   // 4194304 f4
  const int row = (int)(idx >> 9);
  const int c4 = ((int)idx & 511) << 2;
  const int orow = ((row >> 4) << 5) | (hi << 4) | (row & 15);
  float4 v = *(const float4*)(in + (long long)row * 2048 + c4);
  us4 o; o[0] = f2bf(v.x); o[1] = f2bf(v.y); o[2] = f2bf(v.z); o[3] = f2bf(v.w);
  *(us4*)(out + (long long)orow * 2048 + c4) = o;
}

// ---------------- [z][R][C] f32 -> [z][C][R] bf16 (MODE1: interleave rows) --
template<int MODE>
__global__ __launch_bounds__(256) void transpose_cvt(const float* __restrict__ in,
    unsigned short* __restrict__ out, int R, int C)
{
  __shared__ float tile[32][33];
  const long long z = blockIdx.z;
  const float* ip = in + z * (long long)R * C;
  unsigned short* op = out + z * (long long)R * C;
  const int r0 = blockIdx.y * 32, c0 = blockIdx.x * 32;
  const int t = threadIdx.x;
  const int lr = t >> 3, lc = (t & 7) * 4;
  float4 v = *(const float4*)(ip + (long long)(r0 + lr) * C + c0 + lc);
  tile[lr][lc+0] = v.x; tile[lr][lc+1] = v.y; tile[lr][lc+2] = v.z; tile[lr][lc+3] = v.w;
  __syncthreads();
  const int oc = t >> 3, orr = (t & 7) * 4;
  us4 o;
  o[0] = f2bf(tile[orr+0][oc]); o[1] = f2bf(tile[orr+1][oc]);
  o[2] = f2bf(tile[orr+2][oc]); o[3] = f2bf(tile[orr+3][oc]);
  int c = c0 + oc;
  int orow;
  if (MODE == 1)
    orow = (c < 1536) ? (((c >> 4) << 5) | (c & 15))
                      : ((((c - 1536) >> 4) << 5) | 16 | ((c - 1536) & 15));
  else
    orow = c;
  *(us4*)(op + (long long)orow * R + r0 + orr) = o;
}

// ---------------- router: top-4, softmax gating, z-loss ----------------
__global__ void router_topk(const float* __restrict__ logits, int* __restrict__ topk,
                            float* __restrict__ gating, float* __restrict__ zout)
{
  const int t = threadIdx.x, w = t >> 6, lane = t & 63;
  const int n = blockIdx.x * 4 + w;
  const float lg = logits[(long long)n * 64 + lane];
  float z = lg * lg;
#pragma unroll
  for (int off = 32; off; off >>= 1) z += __shfl_xor(z, off);
  __shared__ float zs[4];
  if (lane == 0) zs[w] = z;
  __syncthreads();
  if (t == 0) atomicAdd(zout, (zs[0]+zs[1]+zs[2]+zs[3]) * (0.0001f / 262144.0f));

  float cur = lg;
  float tl[4]; int ti[4];
#pragma unroll
  for (int k = 0; k < 4; ++k){
    float s = cur; int si = lane;
#pragma unroll
    for (int off = 32; off; off >>= 1){
      float so = __shfl_xor(s, off); int io = __shfl_xor(si, off);
      if (so > s || (so == s && io < si)){ s = so; si = io; }
    }
    tl[k] = s; ti[k] = si;
    if (lane == si) cur = -3.0e38f;
  }
  if (lane == 0){
    const float m0 = tl[0];
    const float e0 = __expf(tl[0]-m0), e1 = __expf(tl[1]-m0),
                e2 = __expf(tl[2]-m0), e3 = __expf(tl[3]-m0);
    const float inv = 1.0f / (e0 + e1 + e2 + e3);
    topk[n*4+0] = ti[0]; topk[n*4+1] = ti[1]; topk[n*4+2] = ti[2]; topk[n*4+3] = ti[3];
    gating[n*4+0] = e0*inv; gating[n*4+1] = e1*inv; gating[n*4+2] = e2*inv; gating[n*4+3] = e3*inv;
  }
}

// ---------------- deterministic per-expert rank scan ----------------
__global__ void scan_route(const int* __restrict__ topk, int* __restrict__ gm,
                           int* __restrict__ rev, int* __restrict__ counts)
{
  const int e = blockIdx.x;
  const int t = threadIdx.x, w = t >> 6, lane = t & 63;
  __shared__ int wtot[4];
  int running = 0;
  for (int c = 0; c < 16384; c += 256){
    const int j = c + t;
    const bool p = (topk[j] == e);
    const unsigned long long m = __ballot(p);
    const int prefix = __popcll(m & ((1ull << lane) - 1ull));
    if (lane == 0) wtot[w] = __popcll(m);
    __syncthreads();
    int woff = 0;
#pragma unroll
    for (int i = 0; i < 4; ++i){ if (i < w) woff += wtot[i]; }
    const int btot = wtot[0] + wtot[1] + wtot[2] + wtot[3];
    if (p){
      const int rank = running + woff + prefix;
      gm[j] = (rank < MAXLD) ? (e * MAXLD + rank) : NSLOT;
      if (rank < MAXLD) rev[e * MAXLD + rank] = j >> 2;
    }
    running += btot;
    __syncthreads();
  }
  if (t == 0) counts[e] = running;
}

// ---------------- gather down-projected tokens into expert slots ----------------
__global__ void gather_pad(const unsigned short* __restrict__ down, const int* __restrict__ rev,
                           const int* __restrict__ counts, unsigned short* __restrict__ pad)
{
  const int idx = blockIdx.x * 256 + threadIdx.x;
  const int s = idx >> 6, c8 = (idx & 63) * 8;
  const int e = s / MAXLD;
  const int r = s - e * MAXLD;
  int cnt = counts[e]; if (cnt > MAXLD) cnt = MAXLD;
  us8 v = {0,0,0,0,0,0,0,0};
  if (r < cnt){
    const int tok = rev[s];
    v = *(const us8*)(down + (long long)tok * 512 + c8);
  }
  *(us8*)(pad + (long long)s * 512 + c8) = v;
}

// ---------------- gating-weighted combine ----------------
__global__ void combine_moe(const unsigned short* __restrict__ po, const int* __restrict__ gm,
                            const float* __restrict__ gating, unsigned short* __restrict__ routed)
{
  const int idx = blockIdx.x * 256 + threadIdx.x;
  const int n = idx >> 6, c8 = (idx & 63) * 8;
  float acc[8] = {0,0,0,0,0,0,0,0};
#pragma unroll
  for (int k = 0; k < 4; ++k){
    const int slot = gm[n*4 + k];
    if (slot < NSLOT){
      const float gw = gating[n*4 + k];
      us8 v = *(const us8*)(po + (long long)slot * 512 + c8);
#pragma unroll
      for (int j = 0; j < 8; ++j) acc[j] += gw * bf2f(v[j]);
    }
  }
  us8 o;
#pragma unroll
  for (int j = 0; j < 8; ++j) o[j] = f2bf(acc[j]);
  *(us8*)(routed + (long long)n * 512 + c8) = o;
}

// =====================================================================
extern "C" void kernel_launch(void* const* d_in, const int* in_sizes, int n_in,
                              void* d_out, int out_size, void* d_ws, size_t ws_size,
                              hipStream_t stream)
{
  const float* x      = (const float*)d_in[0];
  const float* rw     = (const float*)d_in[1];
  const float* gate_w = (const float*)d_in[2];
  const float* up_w   = (const float*)d_in[3];
  const float* down_w = (const float*)d_in[4];
  const float* w_down = (const float*)d_in[5];
  const float* w_up   = (const float*)d_in[6];
  const float* w12    = (const float*)d_in[7];
  const float* w3     = (const float*)d_in[8];
  float* out = (float*)d_out;

  char* ws = (char*)d_ws;
  unsigned short* HBF   = (unsigned short*)(ws + 0ull);            // 16.78 MB
  unsigned short* BBIG  = (unsigned short*)(ws + 16777216ull);     // 70.25 MB [17152][2048]
  unsigned short* DWB   = (unsigned short*)(ws + 87031808ull);     // 33.55 MB
  unsigned short* WUB   = (unsigned short*)(ws + 120586240ull);    // 2.10 MB
  unsigned short* W12I  = (unsigned short*)(ws + 122683392ull);    // 201.3 MB interleaved
  unsigned short* W3T   = (unsigned short*)(ws + 324009984ull);    // 100.7 MB
  float*          LOGIT = (float*)(ws + 424673280ull);             // 1.05 MB
  int*            TOPKI = (int*)(ws + 425721856ull);
  float*          GATE4 = (float*)(ws + 425787392ull);
  int*            GM    = (int*)(ws + 425852928ull);
  int*            CNT   = (int*)(ws + 425918464ull);
  int*            REV   = (int*)(ws + 425919488ull);
  unsigned short* ACTS  = (unsigned short*)(ws + 426000384ull);    // 67.1 MB [4096][8192]
  unsigned short* AEXP  = (unsigned short*)(ws + 493109248ull);    // 59.8 MB [E][304][1536]
  float*          SHRD  = (float*)(ws + 552878080ull);             // 67.1 MB (2 K-halves)
  unsigned short* DNB   = (unsigned short*)(ws + 619987072ull);    // 4.19 MB
  unsigned short* PAD   = (unsigned short*)(ws + 624181376ull);    // 19.92 MB
  unsigned short* PO    = (unsigned short*)(ws + 644104192ull);    // 19.92 MB
  unsigned short* RTD   = (unsigned short*)(ws + 664027136ull);    // 4.19 MB (end ~668 MB)

  // z-loss slot + zero-pad rows of BBIG (router pad 16960..17151)
  hipMemsetAsync((char*)d_out + 8388608ull * 4, 0, 4, stream);
  hipMemsetAsync(BBIG + 16960ull * 2048, 0, 192ull * 2048 * 2, stream);

  // bf16 conversions / layout builds
  cvt_bf16<<<8192,  256, 0, stream>>>(x, HBF, 2097152);
  cvt_rowmap<<<16384, 256, 0, stream>>>(gate_w, BBIG, 0);
  cvt_rowmap<<<16384, 256, 0, stream>>>(up_w,   BBIG, 1);
  cvt_bf16<<<1024,  256, 0, stream>>>(w_down, BBIG + 16384ull * 2048, 262144);
  cvt_bf16<<<128,   256, 0, stream>>>(rw,     BBIG + 16896ull * 2048, 32768);
  cvt_bf16<<<16384, 256, 0, stream>>>(down_w, DWB, 4194304);
  cvt_bf16<<<1024,  256, 0, stream>>>(w_up,   WUB, 262144);
  transpose_cvt<1><<<dim3(96,16,64), 256, 0, stream>>>(w12, W12I, 512, 3072);
  transpose_cvt<0><<<dim3(16,48,64), 256, 0, stream>>>(w3,  W3T,  1536, 512);

  // MEGA GEMM: gate+up (fused silu) + w_down + router logits in one pass
  gemm2<256,3><<<dim3(67,16,1), 512, 0, stream>>>(HBF, BBIG, ACTS, nullptr, nullptr,
      4096, 17152, 2048, 2048, 2048, 0, 0, 0, DNB, LOGIT);

  // routing
  router_topk<<<1024, 256, 0, stream>>>(LOGIT, TOPKI, GATE4, out + 8388608);
  scan_route<<<64, 256, 0, stream>>>(TOPKI, GM, REV, CNT);

  // shared down-proj: split-K=2 via grid.z, BM=256, full-chip 256 blocks
  gemm2<256,1><<<dim3(8,16,2), 512, 0, stream>>>(ACTS, DWB, SHRD, nullptr, nullptr,
      4096, 2048, 4096, 8192, 8192, 4096LL, 4096LL, 8388608LL, nullptr, nullptr);

  gather_pad<<<4864, 256, 0, stream>>>(DNB, REV, CNT, PAD);

  // expert MLPs (grouped gemm2; silu fused via interleaved W12I)
  gemm2<128,4><<<dim3(12,3,64), 512, 0, stream>>>(PAD, W12I, AEXP, nullptr, nullptr,
      304, 3072, 512, 512, 512, 155648LL, 1572864LL, 466944LL, nullptr, nullptr);
  gemm2<128,0><<<dim3(2,3,64), 512, 0, stream>>>(AEXP, W3T, PO, nullptr, nullptr,
      304, 512, 1536, 1536, 1536, 466944LL, 786432LL, 155648LL, nullptr, nullptr);
  combine_moe<<<1024, 256, 0, stream>>>(PO, GM, GATE4, RTD);

  // final: out = (shared0 + shared1 + routed @ w_up^T) * 0.5
  gemm2<128,2><<<dim3(8,32,1), 512, 0, stream>>>(RTD, WUB, out, SHRD, SHRD + 8388608,
      4096, 2048, 512, 512, 512, 0, 0, 0, nullptr, nullptr);
}